// Round 3
// baseline (322.823 us; speedup 1.0000x reference)
//
#include <hip/hip_runtime.h>
#include <hip/hip_bf16.h>
#include <stdint.h>

#define N_ROWS 262144
#define FEAT 1024
#define N_CORES 4096
#define HDIM 1024
#define BN_EPS 1e-5f

typedef __attribute__((ext_vector_type(8))) short bf16x8;
typedef __attribute__((ext_vector_type(8))) unsigned short u16x8;
typedef __attribute__((ext_vector_type(4))) float f32x4;

__device__ __forceinline__ unsigned short f2bf(float f) {
  __hip_bfloat16 h = __float2bfloat16(f);
  return __builtin_bit_cast(unsigned short, h);
}
__device__ __forceinline__ float bf2f(unsigned short u) {
  unsigned int x = ((unsigned int)u) << 16;
  return __builtin_bit_cast(float, x);
}

// async global->LDS, 16B per lane, dest = uniform base + lane*16
__device__ __forceinline__ void gll16(const unsigned short* g, unsigned short* l) {
  __builtin_amdgcn_global_load_lds(
      (const __attribute__((address_space(1))) void*)g,
      (__attribute__((address_space(3))) void*)l, 16, 0, 0);
}

// ---------------------------------------------------------------- seg-sum
__global__ __launch_bounds__(256)
void k_segsum(const float* __restrict__ x, const int* __restrict__ corelen,
              unsigned short* __restrict__ aggb) {
  const int seg = blockIdx.x;
  const int t = threadIdx.x;
  const int start = corelen[seg];
  const int end = (seg + 1 < N_CORES) ? corelen[seg + 1] : N_ROWS;
  float4 a0 = make_float4(0.f, 0.f, 0.f, 0.f);
  float4 a1 = make_float4(0.f, 0.f, 0.f, 0.f);
  const float* xp = x + (size_t)start * FEAT + t * 4;
  int r = start;
  for (; r + 2 <= end; r += 2) {
    const float4 v0 = *(const float4*)xp;
    const float4 v1 = *(const float4*)(xp + FEAT);
    a0.x += v0.x; a0.y += v0.y; a0.z += v0.z; a0.w += v0.w;
    a1.x += v1.x; a1.y += v1.y; a1.z += v1.z; a1.w += v1.w;
    xp += 2 * FEAT;
  }
  if (r < end) {
    const float4 v0 = *(const float4*)xp;
    a0.x += v0.x; a0.y += v0.y; a0.z += v0.z; a0.w += v0.w;
  }
  a0.x += a1.x; a0.y += a1.y; a0.z += a1.z; a0.w += a1.w;
  ushort4 o;
  o.x = f2bf(a0.x); o.y = f2bf(a0.y); o.z = f2bf(a0.z); o.w = f2bf(a0.w);
  *(ushort4*)(aggb + (size_t)seg * FEAT + t * 4) = o;
}

// ---------------------- all three W [K,N] f32 -> Wt [N,K] bf16 in one launch
__global__ __launch_bounds__(256)
void k_transpose_all(const float* __restrict__ W1, const float* __restrict__ W2,
                     const float* __restrict__ W3, unsigned short* __restrict__ Wt) {
  __shared__ unsigned short tile[32][33];
  const int l = blockIdx.z;
  const float* W = (l == 0) ? W1 : (l == 1) ? W2 : W3;
  unsigned short* Wo = Wt + (size_t)l * HDIM * HDIM;
  const int tx = threadIdx.x, ty = threadIdx.y;
  const int n0 = blockIdx.x * 32, k0 = blockIdx.y * 32;
#pragma unroll
  for (int i = 0; i < 4; ++i)
    tile[ty + 8 * i][tx] = f2bf(W[(size_t)(k0 + ty + 8 * i) * HDIM + n0 + tx]);
  __syncthreads();
#pragma unroll
  for (int i = 0; i < 4; ++i)
    Wo[(size_t)(n0 + ty + 8 * i) * HDIM + k0 + tx] = tile[tx][ty + 8 * i];
}

// ------------------------------------------------------------------ GEMM
// C[M,N](bf16) = A[M,K](bf16) * Bt[N,K](bf16)^T + bias, fused BN col stats.
// BM=128, BN=64, BK=64; 4 waves, wave tile 64x32 (4x2 frags 16x16x32).
// 2-phase double-buffered LDS: STAGE(t+1) issued BEFORE compute(t); the
// single loop-end __syncthreads drains exactly the next-tile loads after
// they've had the whole MFMA phase to fly (T3 minimum recipe).
// XOR-swizzled gll16 source cols + matching ds_read swizzle (T2, rule 21).
// XCD-chunked 1D grid (T1): each XCD keeps 2 B-panels L2-hot.
#define BM 128
#define BN 64
#define BK 64
#define NT (HDIM / BK)
__global__ __launch_bounds__(256)
void k_gemm_bt(const unsigned short* __restrict__ A,
               const unsigned short* __restrict__ Bt,
               const float* __restrict__ bias,
               unsigned short* __restrict__ C,
               float* __restrict__ sums, float* __restrict__ sumsq) {
  __shared__ unsigned short As[2][BM * BK];
  __shared__ unsigned short Bs[2][BN * BK];
  const int t = threadIdx.x;
  const int lane = t & 63;
  const int w = t >> 6;
  // bijective XCD-chunked swizzle: grid 512 = 8 XCDs x 64
  const int bid = blockIdx.x;
  const int rm = (bid & 7) * 64 + (bid >> 3);
  const int tileM = (rm & 31) * BM;
  const int tileN = (rm >> 5) * BN;
  const int wr = (w >> 1) * 64;   // wave row origin
  const int wc = (w & 1) * 32;    // wave col origin
  const int fr = lane & 15;
  const int kk = (lane >> 4) * 8;
  const int lr = lane >> 3;                       // staging sub-row 0..7
  const int sc = ((lane & 7) * 8) ^ (lr << 3);    // swizzled source k-col

  const unsigned short* pA = A + (size_t)(tileM + w * 32 + lr) * HDIM + sc;
  const unsigned short* pB = Bt + (size_t)(tileN + w * 16 + lr) * HDIM + sc;

  f32x4 acc[4][2] = {};

#define STAGE(buf, k0)                                                   \
  {                                                                      \
    _Pragma("unroll") for (int j = 0; j < 4; ++j)                        \
        gll16(pA + (k0) + j * 8 * HDIM, &As[buf][(w * 32 + j * 8) * BK]);\
    _Pragma("unroll") for (int j = 0; j < 2; ++j)                        \
        gll16(pB + (k0) + j * 8 * HDIM, &Bs[buf][(w * 16 + j * 8) * BK]);\
  }

  STAGE(0, 0);
  __syncthreads();
  for (int kt = 0; kt < NT; ++kt) {
    const int cur = kt & 1;
    if (kt < NT - 1) STAGE(cur ^ 1, (kt + 1) * BK);
#pragma unroll
    for (int ks = 0; ks < 2; ++ks) {
      const int pc = (ks * 32 + kk) ^ ((fr & 7) << 3);  // swizzled read col
      bf16x8 af[4], bfv[2];
#pragma unroll
      for (int m = 0; m < 4; ++m)
        af[m] = *(const bf16x8*)&As[cur][(wr + m * 16 + fr) * BK + pc];
#pragma unroll
      for (int n = 0; n < 2; ++n)
        bfv[n] = *(const bf16x8*)&Bs[cur][(wc + n * 16 + fr) * BK + pc];
#pragma unroll
      for (int m = 0; m < 4; ++m)
#pragma unroll
        for (int n = 0; n < 2; ++n)
          acc[m][n] = __builtin_amdgcn_mfma_f32_16x16x32_bf16(af[m], bfv[n], acc[m][n], 0, 0, 0);
    }
    __syncthreads();  // drains next-tile vmcnt (loads had full compute to fly)
  }
#undef STAGE

  // epilogue: bias, store bf16 H, fused per-column partial BN stats (f32)
  const int cr = (lane >> 4) * 4;
  const int cc = lane & 15;
#pragma unroll
  for (int n = 0; n < 2; ++n) {
    const int col = tileN + wc + n * 16 + cc;
    const float bv = bias[col];
    float s = 0.f, s2 = 0.f;
#pragma unroll
    for (int m = 0; m < 4; ++m) {
      unsigned short* cp = C + (size_t)(tileM + wr + m * 16 + cr) * HDIM + col;
#pragma unroll
      for (int j = 0; j < 4; ++j) {
        const float h = acc[m][n][j] + bv;
        cp[(size_t)j * HDIM] = f2bf(h);
        s += h; s2 += h * h;
      }
    }
    s  += __shfl_xor(s, 16, 64);  s  += __shfl_xor(s, 32, 64);
    s2 += __shfl_xor(s2, 16, 64); s2 += __shfl_xor(s2, 32, 64);
    if ((lane >> 4) == 0) {
      atomicAdd(&sums[col], s);
      atomicAdd(&sumsq[col], s2);
    }
  }
}

__global__ __launch_bounds__(256)
void k_finalize(const float* __restrict__ sums, const float* __restrict__ sumsq,
                const float* __restrict__ g, const float* __restrict__ be,
                float* __restrict__ scale, float* __restrict__ shift) {
  const int c = blockIdx.x * 256 + threadIdx.x;
  const float mean = sums[c] * (1.f / N_CORES);
  const float var = sumsq[c] * (1.f / N_CORES) - mean * mean;
  const float sc = g[c] * rsqrtf(var + BN_EPS);
  scale[c] = sc;
  shift[c] = be[c] - mean * sc;
}

// ---------------------------------------- normalize + ReLU (bf16 in/out)
__global__ __launch_bounds__(256)
void k_norm_relu(const unsigned short* __restrict__ Hb, const float* __restrict__ scale,
                 const float* __restrict__ shift, unsigned short* __restrict__ Ab) {
  const size_t i8 = ((size_t)blockIdx.x * 256 + threadIdx.x) * 8;
  const u16x8 v = *(const u16x8*)(Hb + i8);
  const int c = (int)(i8 & (HDIM - 1));
  const float4 sc0 = *(const float4*)(scale + c);
  const float4 sc1 = *(const float4*)(scale + c + 4);
  const float4 sh0 = *(const float4*)(shift + c);
  const float4 sh1 = *(const float4*)(shift + c + 4);
  u16x8 o;
  o[0] = f2bf(fmaxf(bf2f(v[0]) * sc0.x + sh0.x, 0.f));
  o[1] = f2bf(fmaxf(bf2f(v[1]) * sc0.y + sh0.y, 0.f));
  o[2] = f2bf(fmaxf(bf2f(v[2]) * sc0.z + sh0.z, 0.f));
  o[3] = f2bf(fmaxf(bf2f(v[3]) * sc0.w + sh0.w, 0.f));
  o[4] = f2bf(fmaxf(bf2f(v[4]) * sc1.x + sh1.x, 0.f));
  o[5] = f2bf(fmaxf(bf2f(v[5]) * sc1.y + sh1.y, 0.f));
  o[6] = f2bf(fmaxf(bf2f(v[6]) * sc1.z + sh1.z, 0.f));
  o[7] = f2bf(fmaxf(bf2f(v[7]) * sc1.w + sh1.w, 0.f));
  *(u16x8*)(Ab + i8) = o;
}

// ----------------------------------------------- final layer [4096,1024]x[1024,2]
__global__ __launch_bounds__(256)
void k_final(const unsigned short* __restrict__ Ab, const float* __restrict__ W4,
             const float* __restrict__ b4, float* __restrict__ out) {
  const int t = threadIdx.x;
  const int w = t >> 6, lane = t & 63;
  const int row = blockIdx.x * 4 + w;
  const unsigned short* a = Ab + (size_t)row * HDIM + lane * 16;
  const bf16x8 v0 = *(const bf16x8*)a;
  const bf16x8 v1 = *(const bf16x8*)(a + 8);
  float s0 = 0.f, s1 = 0.f;
  const int kbase = lane * 16;
#pragma unroll
  for (int j = 0; j < 8; ++j) {
    const float av = bf2f((unsigned short)v0[j]);
    s0 += av * W4[(kbase + j) * 2 + 0];
    s1 += av * W4[(kbase + j) * 2 + 1];
  }
#pragma unroll
  for (int j = 0; j < 8; ++j) {
    const float av = bf2f((unsigned short)v1[j]);
    s0 += av * W4[(kbase + 8 + j) * 2 + 0];
    s1 += av * W4[(kbase + 8 + j) * 2 + 1];
  }
#pragma unroll
  for (int off = 32; off >= 1; off >>= 1) {
    s0 += __shfl_down(s0, off, 64);
    s1 += __shfl_down(s1, off, 64);
  }
  if (lane == 0) {
    out[row * 2 + 0] = s0 + b4[0];
    out[row * 2 + 1] = s1 + b4[1];
  }
}

extern "C" void kernel_launch(void* const* d_in, const int* in_sizes, int n_in,
                              void* d_out, int out_size, void* d_ws, size_t ws_size,
                              hipStream_t stream) {
  (void)in_sizes; (void)n_in; (void)out_size; (void)ws_size;
  const float* x       = (const float*)d_in[0];
  const int* corelen   = (const int*)d_in[1];
  const float* W1  = (const float*)d_in[2];
  const float* b1  = (const float*)d_in[3];
  const float* g1  = (const float*)d_in[4];
  const float* be1 = (const float*)d_in[5];
  const float* W2  = (const float*)d_in[6];
  const float* b2  = (const float*)d_in[7];
  const float* g2  = (const float*)d_in[8];
  const float* be2 = (const float*)d_in[9];
  const float* W3  = (const float*)d_in[10];
  const float* b3  = (const float*)d_in[11];
  const float* g3  = (const float*)d_in[12];
  const float* be3 = (const float*)d_in[13];
  const float* W4  = (const float*)d_in[14];
  const float* b4  = (const float*)d_in[15];
  float* out = (float*)d_out;

  char* ws = (char*)d_ws;
  unsigned short* Hb   = (unsigned short*)(ws);               //  8 MB [4096,1024] bf16 (pre-BN)
  unsigned short* Abf  = (unsigned short*)(ws + (8u << 20));  //  8 MB [4096,1024] bf16 (activations)
  unsigned short* Wt   = (unsigned short*)(ws + (16u << 20)); //  6 MB 3x[1024,1024] bf16
  float* stats = (float*)(ws + (22u << 20));                  // 6*1024 f32 (per-layer sums/sumsq)
  float* scale = stats + 6 * HDIM;
  float* shift = scale + HDIM;

  hipMemsetAsync(stats, 0, 6 * HDIM * sizeof(float), stream);
  k_transpose_all<<<dim3(32, 32, 3), dim3(32, 8), 0, stream>>>(W1, W2, W3, Wt);
  k_segsum<<<N_CORES, 256, 0, stream>>>(x, corelen, Abf);

  const float* bs[3]  = {b1, b2, b3};
  const float* gs[3]  = {g1, g2, g3};
  const float* bes[3] = {be1, be2, be3};
  for (int l = 0; l < 3; ++l) {
    float* sums  = stats + l * 2 * HDIM;
    float* sumsq = sums + HDIM;
    k_gemm_bt<<<(N_CORES / BM) * (HDIM / BN), 256, 0, stream>>>(
        Abf, Wt + (size_t)l * HDIM * HDIM, bs[l], Hb, sums, sumsq);
    k_finalize<<<HDIM / 256, 256, 0, stream>>>(sums, sumsq, gs[l], bes[l], scale, shift);
    k_norm_relu<<<(N_CORES * HDIM / 8) / 256, 256, 0, stream>>>(Hb, scale, shift, Abf);
  }
  k_final<<<N_CORES / 4, 256, 0, stream>>>(Abf, W4, b4, out);
}

// Round 4
// 312.086 us; speedup vs baseline: 1.0344x; 1.0344x over previous
//
#include <hip/hip_runtime.h>
#include <hip/hip_bf16.h>
#include <stdint.h>

#define N_ROWS 262144
#define FEAT 1024
#define N_CORES 4096
#define HDIM 1024
#define BN_EPS 1e-5f

typedef __attribute__((ext_vector_type(8))) short bf16x8;
typedef __attribute__((ext_vector_type(8))) unsigned short u16x8;
typedef __attribute__((ext_vector_type(4))) float f32x4;

__device__ __forceinline__ unsigned short f2bf(float f) {
  __hip_bfloat16 h = __float2bfloat16(f);
  return __builtin_bit_cast(unsigned short, h);
}
__device__ __forceinline__ float bf2f(unsigned short u) {
  unsigned int x = ((unsigned int)u) << 16;
  return __builtin_bit_cast(float, x);
}

// async global->LDS, 16B per lane, dest = uniform base + lane*16
__device__ __forceinline__ void gll16(const unsigned short* g, unsigned short* l) {
  __builtin_amdgcn_global_load_lds(
      (const __attribute__((address_space(1))) void*)g,
      (__attribute__((address_space(3))) void*)l, 16, 0, 0);
}

// ---------------------------------------------------------------- seg-sum
__global__ __launch_bounds__(256)
void k_segsum(const float* __restrict__ x, const int* __restrict__ corelen,
              unsigned short* __restrict__ aggb) {
  const int seg = blockIdx.x;
  const int t = threadIdx.x;
  const int start = corelen[seg];
  const int end = (seg + 1 < N_CORES) ? corelen[seg + 1] : N_ROWS;
  float4 a0 = make_float4(0.f, 0.f, 0.f, 0.f);
  float4 a1 = make_float4(0.f, 0.f, 0.f, 0.f);
  const float* xp = x + (size_t)start * FEAT + t * 4;
  int r = start;
  for (; r + 2 <= end; r += 2) {
    const float4 v0 = *(const float4*)xp;
    const float4 v1 = *(const float4*)(xp + FEAT);
    a0.x += v0.x; a0.y += v0.y; a0.z += v0.z; a0.w += v0.w;
    a1.x += v1.x; a1.y += v1.y; a1.z += v1.z; a1.w += v1.w;
    xp += 2 * FEAT;
  }
  if (r < end) {
    const float4 v0 = *(const float4*)xp;
    a0.x += v0.x; a0.y += v0.y; a0.z += v0.z; a0.w += v0.w;
  }
  a0.x += a1.x; a0.y += a1.y; a0.z += a1.z; a0.w += a1.w;
  ushort4 o;
  o.x = f2bf(a0.x); o.y = f2bf(a0.y); o.z = f2bf(a0.z); o.w = f2bf(a0.w);
  *(ushort4*)(aggb + (size_t)seg * FEAT + t * 4) = o;
}

// ---------------------- all three W [K,N] f32 -> Wt [N,K] bf16 in one launch
__global__ __launch_bounds__(256)
void k_transpose_all(const float* __restrict__ W1, const float* __restrict__ W2,
                     const float* __restrict__ W3, unsigned short* __restrict__ Wt) {
  __shared__ unsigned short tile[32][33];
  const int l = blockIdx.z;
  const float* W = (l == 0) ? W1 : (l == 1) ? W2 : W3;
  unsigned short* Wo = Wt + (size_t)l * HDIM * HDIM;
  const int tx = threadIdx.x, ty = threadIdx.y;
  const int n0 = blockIdx.x * 32, k0 = blockIdx.y * 32;
#pragma unroll
  for (int i = 0; i < 4; ++i)
    tile[ty + 8 * i][tx] = f2bf(W[(size_t)(k0 + ty + 8 * i) * HDIM + n0 + tx]);
  __syncthreads();
#pragma unroll
  for (int i = 0; i < 4; ++i)
    Wo[(size_t)(n0 + ty + 8 * i) * HDIM + k0 + tx] = tile[tx][ty + 8 * i];
}

// ------------------------------------------------------------------ GEMM
// C[M,N](bf16) = A[M,K](bf16) * Bt[N,K](bf16)^T + bias, fused BN col stats.
// BM=128, BN=64, BK=64; 4 waves, wave tile 64x32 (4x2 frags 16x16x32).
// 2-phase double-buffered LDS (T3 minimum): STAGE(t+1) issued BEFORE
// compute(t); single loop-end __syncthreads drains next-tile loads after
// a full MFMA phase of flight.
// NATURAL 2D grid (no XCD swizzle): bid=y*32+x round-robins x across XCDs,
// so each XCD keeps a 1MB A-slice (4 M-tiles) L2-resident across the whole
// y sweep and streams only B (R3 lesson: custom swizzle streamed 8MB A per
// XCD -> +22us).
#define BM 128
#define BN 64
#define BK 64
#define NT (HDIM / BK)
__global__ __launch_bounds__(256)
void k_gemm_bt(const unsigned short* __restrict__ A,
               const unsigned short* __restrict__ Bt,
               const float* __restrict__ bias,
               unsigned short* __restrict__ C,
               float* __restrict__ sums, float* __restrict__ sumsq) {
  __shared__ unsigned short As[2][BM * BK];
  __shared__ unsigned short Bs[2][BN * BK];
  const int t = threadIdx.x;
  const int lane = t & 63;
  const int w = t >> 6;
  const int tileM = blockIdx.x * BM;
  const int tileN = blockIdx.y * BN;
  const int wr = (w >> 1) * 64;   // wave row origin
  const int wc = (w & 1) * 32;    // wave col origin
  const int fr = lane & 15;
  const int kk = (lane >> 4) * 8;
  const int lr = lane >> 3;                       // staging sub-row 0..7
  const int sc = ((lane & 7) * 8) ^ (lr << 3);    // swizzled source k-col

  const unsigned short* pA = A + (size_t)(tileM + w * 32 + lr) * HDIM + sc;
  const unsigned short* pB = Bt + (size_t)(tileN + w * 16 + lr) * HDIM + sc;

  f32x4 acc[4][2] = {};

#define STAGE(buf, k0)                                                   \
  {                                                                      \
    _Pragma("unroll") for (int j = 0; j < 4; ++j)                        \
        gll16(pA + (k0) + j * 8 * HDIM, &As[buf][(w * 32 + j * 8) * BK]);\
    _Pragma("unroll") for (int j = 0; j < 2; ++j)                        \
        gll16(pB + (k0) + j * 8 * HDIM, &Bs[buf][(w * 16 + j * 8) * BK]);\
  }

  STAGE(0, 0);
  __syncthreads();
  for (int kt = 0; kt < NT; ++kt) {
    const int cur = kt & 1;
    if (kt < NT - 1) STAGE(cur ^ 1, (kt + 1) * BK);
#pragma unroll
    for (int ks = 0; ks < 2; ++ks) {
      const int pc = (ks * 32 + kk) ^ ((fr & 7) << 3);  // swizzled read col
      bf16x8 af[4], bfv[2];
#pragma unroll
      for (int m = 0; m < 4; ++m)
        af[m] = *(const bf16x8*)&As[cur][(wr + m * 16 + fr) * BK + pc];
#pragma unroll
      for (int n = 0; n < 2; ++n)
        bfv[n] = *(const bf16x8*)&Bs[cur][(wc + n * 16 + fr) * BK + pc];
#pragma unroll
      for (int m = 0; m < 4; ++m)
#pragma unroll
        for (int n = 0; n < 2; ++n)
          acc[m][n] = __builtin_amdgcn_mfma_f32_16x16x32_bf16(af[m], bfv[n], acc[m][n], 0, 0, 0);
    }
    __syncthreads();  // drains next-tile vmcnt (loads had full compute to fly)
  }
#undef STAGE

  // epilogue: bias, store bf16 H, fused per-column partial BN stats (f32)
  const int cr = (lane >> 4) * 4;
  const int cc = lane & 15;
#pragma unroll
  for (int n = 0; n < 2; ++n) {
    const int col = tileN + wc + n * 16 + cc;
    const float bv = bias[col];
    float s = 0.f, s2 = 0.f;
#pragma unroll
    for (int m = 0; m < 4; ++m) {
      unsigned short* cp = C + (size_t)(tileM + wr + m * 16 + cr) * HDIM + col;
#pragma unroll
      for (int j = 0; j < 4; ++j) {
        const float h = acc[m][n][j] + bv;
        cp[(size_t)j * HDIM] = f2bf(h);
        s += h; s2 += h * h;
      }
    }
    s  += __shfl_xor(s, 16, 64);  s  += __shfl_xor(s, 32, 64);
    s2 += __shfl_xor(s2, 16, 64); s2 += __shfl_xor(s2, 32, 64);
    if ((lane >> 4) == 0) {
      atomicAdd(&sums[col], s);
      atomicAdd(&sumsq[col], s2);
    }
  }
}

__global__ __launch_bounds__(256)
void k_finalize(const float* __restrict__ sums, const float* __restrict__ sumsq,
                const float* __restrict__ g, const float* __restrict__ be,
                float* __restrict__ scale, float* __restrict__ shift) {
  const int c = blockIdx.x * 256 + threadIdx.x;
  const float mean = sums[c] * (1.f / N_CORES);
  const float var = sumsq[c] * (1.f / N_CORES) - mean * mean;
  const float sc = g[c] * rsqrtf(var + BN_EPS);
  scale[c] = sc;
  shift[c] = be[c] - mean * sc;
}

// ---------------------------------------- normalize + ReLU (bf16 in/out)
__global__ __launch_bounds__(256)
void k_norm_relu(const unsigned short* __restrict__ Hb, const float* __restrict__ scale,
                 const float* __restrict__ shift, unsigned short* __restrict__ Ab) {
  const size_t i8 = ((size_t)blockIdx.x * 256 + threadIdx.x) * 8;
  const u16x8 v = *(const u16x8*)(Hb + i8);
  const int c = (int)(i8 & (HDIM - 1));
  const float4 sc0 = *(const float4*)(scale + c);
  const float4 sc1 = *(const float4*)(scale + c + 4);
  const float4 sh0 = *(const float4*)(shift + c);
  const float4 sh1 = *(const float4*)(shift + c + 4);
  u16x8 o;
  o[0] = f2bf(fmaxf(bf2f(v[0]) * sc0.x + sh0.x, 0.f));
  o[1] = f2bf(fmaxf(bf2f(v[1]) * sc0.y + sh0.y, 0.f));
  o[2] = f2bf(fmaxf(bf2f(v[2]) * sc0.z + sh0.z, 0.f));
  o[3] = f2bf(fmaxf(bf2f(v[3]) * sc0.w + sh0.w, 0.f));
  o[4] = f2bf(fmaxf(bf2f(v[4]) * sc1.x + sh1.x, 0.f));
  o[5] = f2bf(fmaxf(bf2f(v[5]) * sc1.y + sh1.y, 0.f));
  o[6] = f2bf(fmaxf(bf2f(v[6]) * sc1.z + sh1.z, 0.f));
  o[7] = f2bf(fmaxf(bf2f(v[7]) * sc1.w + sh1.w, 0.f));
  *(u16x8*)(Ab + i8) = o;
}

// ----------------------------------------------- final layer [4096,1024]x[1024,2]
__global__ __launch_bounds__(256)
void k_final(const unsigned short* __restrict__ Ab, const float* __restrict__ W4,
             const float* __restrict__ b4, float* __restrict__ out) {
  const int t = threadIdx.x;
  const int w = t >> 6, lane = t & 63;
  const int row = blockIdx.x * 4 + w;
  const unsigned short* a = Ab + (size_t)row * HDIM + lane * 16;
  const bf16x8 v0 = *(const bf16x8*)a;
  const bf16x8 v1 = *(const bf16x8*)(a + 8);
  float s0 = 0.f, s1 = 0.f;
  const int kbase = lane * 16;
#pragma unroll
  for (int j = 0; j < 8; ++j) {
    const float av = bf2f((unsigned short)v0[j]);
    s0 += av * W4[(kbase + j) * 2 + 0];
    s1 += av * W4[(kbase + j) * 2 + 1];
  }
#pragma unroll
  for (int j = 0; j < 8; ++j) {
    const float av = bf2f((unsigned short)v1[j]);
    s0 += av * W4[(kbase + 8 + j) * 2 + 0];
    s1 += av * W4[(kbase + 8 + j) * 2 + 1];
  }
#pragma unroll
  for (int off = 32; off >= 1; off >>= 1) {
    s0 += __shfl_down(s0, off, 64);
    s1 += __shfl_down(s1, off, 64);
  }
  if (lane == 0) {
    out[row * 2 + 0] = s0 + b4[0];
    out[row * 2 + 1] = s1 + b4[1];
  }
}

extern "C" void kernel_launch(void* const* d_in, const int* in_sizes, int n_in,
                              void* d_out, int out_size, void* d_ws, size_t ws_size,
                              hipStream_t stream) {
  (void)in_sizes; (void)n_in; (void)out_size; (void)ws_size;
  const float* x       = (const float*)d_in[0];
  const int* corelen   = (const int*)d_in[1];
  const float* W1  = (const float*)d_in[2];
  const float* b1  = (const float*)d_in[3];
  const float* g1  = (const float*)d_in[4];
  const float* be1 = (const float*)d_in[5];
  const float* W2  = (const float*)d_in[6];
  const float* b2  = (const float*)d_in[7];
  const float* g2  = (const float*)d_in[8];
  const float* be2 = (const float*)d_in[9];
  const float* W3  = (const float*)d_in[10];
  const float* b3  = (const float*)d_in[11];
  const float* g3  = (const float*)d_in[12];
  const float* be3 = (const float*)d_in[13];
  const float* W4  = (const float*)d_in[14];
  const float* b4  = (const float*)d_in[15];
  float* out = (float*)d_out;

  char* ws = (char*)d_ws;
  unsigned short* Hb   = (unsigned short*)(ws);               //  8 MB [4096,1024] bf16 (pre-BN)
  unsigned short* Abf  = (unsigned short*)(ws + (8u << 20));  //  8 MB [4096,1024] bf16 (activations)
  unsigned short* Wt   = (unsigned short*)(ws + (16u << 20)); //  6 MB 3x[1024,1024] bf16
  float* stats = (float*)(ws + (22u << 20));                  // 6*1024 f32 (per-layer sums/sumsq)
  float* scale = stats + 6 * HDIM;
  float* shift = scale + HDIM;

  hipMemsetAsync(stats, 0, 6 * HDIM * sizeof(float), stream);
  k_transpose_all<<<dim3(32, 32, 3), dim3(32, 8), 0, stream>>>(W1, W2, W3, Wt);
  k_segsum<<<N_CORES, 256, 0, stream>>>(x, corelen, Abf);

  const float* bs[3]  = {b1, b2, b3};
  const float* gs[3]  = {g1, g2, g3};
  const float* bes[3] = {be1, be2, be3};
  for (int l = 0; l < 3; ++l) {
    float* sums  = stats + l * 2 * HDIM;
    float* sumsq = sums + HDIM;
    k_gemm_bt<<<dim3(N_CORES / BM, HDIM / BN), 256, 0, stream>>>(
        Abf, Wt + (size_t)l * HDIM * HDIM, bs[l], Hb, sums, sumsq);
    k_finalize<<<HDIM / 256, 256, 0, stream>>>(sums, sumsq, gs[l], bes[l], scale, shift);
    k_norm_relu<<<(N_CORES * HDIM / 8) / 256, 256, 0, stream>>>(Hb, scale, shift, Abf);
  }
  k_final<<<N_CORES / 4, 256, 0, stream>>>(Abf, W4, b4, out);
}